// Round 12
// baseline (285.538 us; speedup 1.0000x reference)
//
#include <hip/hip_runtime.h>
#include <math.h>

#define NN 100000
#define NE 1600000
#define NG 64
#define F  128

constexpr int NBUCK = (NN + 127) / 128;     // 782 buckets of 128 nodes
constexpr int NBLK  = 256;                  // hist/place blocks: 1/CU
constexpr int EPB   = (NE + NBLK - 1) / NBLK;  // 6250 edges per block
constexpr int BCAP  = 3072;                 // LDS packed-pair cap per bucket (mean 2046)

typedef __bf16 bf16x8 __attribute__((ext_vector_type(8)));
typedef float  f32x4  __attribute__((ext_vector_type(4)));

__device__ __forceinline__ float b2f(unsigned short u) {
    union { unsigned i; float f; } v; v.i = ((unsigned)u) << 16; return v.f;
}
__device__ __forceinline__ unsigned short f2b(float f) {
    union { float f; unsigned i; } v; v.f = f;
    unsigned i = v.i;
    return (unsigned short)((i + 0x7fffu + ((i >> 16) & 1u)) >> 16);  // RNE
}

// ---------------- sort pipeline 1: per-block bucket histogram (LDS, dense write) --------
__global__ __launch_bounds__(256) void k_hist(const int* __restrict__ dst, int* __restrict__ histg) {
    __shared__ int h[NBUCK];
    int blk = blockIdx.x, t = threadIdx.x;
    for (int b = t; b < NBUCK; b += 256) h[b] = 0;
    __syncthreads();
    int s0 = blk * EPB, s1 = min(s0 + EPB, NE);
    for (int e = s0 + t; e < s1; e += 256) {
        int d = __builtin_nontemporal_load(&dst[e]);
        atomicAdd(&h[d >> 7], 1);
    }
    __syncthreads();
    for (int b = t; b < NBUCK; b += 256) histg[(size_t)blk * NBUCK + b] = h[b];
}

// ---------------- sort pipeline 2: per-bucket scan over NBLK blocks ----------------
__global__ __launch_bounds__(NBLK) void k_boff(const int* __restrict__ histg, int* __restrict__ offs,
                                               int* __restrict__ tot) {
    __shared__ int sh[NBLK];
    int b = blockIdx.x, t = threadIdx.x;
    int v = histg[(size_t)t * NBUCK + b];
    sh[t] = v; __syncthreads();
    for (int d = 1; d < NBLK; d <<= 1) {
        int x = (t >= d) ? sh[t - d] : 0;
        __syncthreads();
        sh[t] += x;
        __syncthreads();
    }
    offs[(size_t)b * NBLK + t] = sh[t] - v;   // exclusive over blocks
    if (t == NBLK - 1) tot[b] = sh[t];
}

// ---------------- sort pipeline 3: exclusive scan of bucket totals (pair layout) --------
__global__ __launch_bounds__(1024) void k_scanb(const int* __restrict__ tot, int* __restrict__ base) {
    __shared__ int sh[1024];
    int t = threadIdx.x;
    int v = (t < NBUCK) ? tot[t] : 0;
    sh[t] = v; __syncthreads();
    for (int d = 1; d < 1024; d <<= 1) {
        int x = (t >= d) ? sh[t - d] : 0;
        __syncthreads();
        sh[t] += x;
        __syncthreads();
    }
    if (t < NBUCK) base[t] = sh[t] - v;      // exclusive
    if (t == NBUCK - 1) base[NBUCK] = sh[t]; // = NE
}

// ---------------- sort pipeline 4: place packed (src<<7|local) bucket-partitioned --------
__global__ __launch_bounds__(256) void k_place(const int* __restrict__ src, const int* __restrict__ dst,
                                               const int* __restrict__ offs, const int* __restrict__ base,
                                               unsigned* __restrict__ pair) {
    __shared__ int cur[NBUCK];
    int blk = blockIdx.x, t = threadIdx.x;
    for (int b = t; b < NBUCK; b += 256) cur[b] = base[b] + offs[(size_t)b * NBLK + blk];
    __syncthreads();
    int s0 = blk * EPB, s1 = min(s0 + EPB, NE);
    for (int e = s0 + t; e < s1; e += 256) {
        int d = __builtin_nontemporal_load(&dst[e]);
        int s = __builtin_nontemporal_load(&src[e]);
        int pos = atomicAdd(&cur[d >> 7], 1);
        pair[pos] = ((unsigned)s << 7) | (unsigned)(d & 127);
    }
}

// ---------------- sort pipeline 5a: per-node degrees, dinv, per-bucket padded totals ----
__global__ __launch_bounds__(256) void k_cnt(const unsigned* __restrict__ pair, const int* __restrict__ base,
                                             float* __restrict__ dinv, int* __restrict__ deg,
                                             int* __restrict__ ptot) {
    __shared__ int c[128];
    __shared__ int red[256];
    int b = blockIdx.x, t = threadIdx.x;
    int s0 = base[b], n = base[b + 1] - s0;
    if (t < 128) c[t] = 0;
    __syncthreads();
    for (int i = t; i < n; i += 256) atomicAdd(&c[pair[s0 + i] & 127u], 1);
    __syncthreads();
    int g0 = b * 128;
    int pd = 0;
    if (t < 128) {
        int d = c[t];
        if (g0 + t < NN) { deg[g0 + t] = d; dinv[g0 + t] = rsqrtf((float)d + 1.0f); }
        pd = (d + 15) & ~15;
    }
    red[t] = pd; __syncthreads();
    for (int dd = 128; dd > 0; dd >>= 1) { if (t < dd) red[t] += red[t + dd]; __syncthreads(); }
    if (t == 0) ptot[b] = red[0];
}

// ---------------- sort pipeline 5b: exclusive scan of padded bucket totals ----------------
__global__ __launch_bounds__(1024) void k_scanp(const int* __restrict__ ptot, int* __restrict__ pbase) {
    __shared__ int sh[1024];
    int t = threadIdx.x;
    int v = (t < NBUCK) ? ptot[t] : 0;
    sh[t] = v; __syncthreads();
    for (int d = 1; d < 1024; d <<= 1) {
        int x = (t >= d) ? sh[t - d] : 0;
        __syncthreads();
        sh[t] += x;
        __syncthreads();
    }
    if (t < NBUCK) pbase[t] = sh[t] - v;
    if (t == NBUCK - 1) pbase[NBUCK] = sh[t];
}

// ---------------- sort pipeline 5c: row_start (padded), col scatter, pad fill ----------
// Pads point to node NN: a dedicated all-zero fp8 row -> spmm needs NO masks.
__global__ __launch_bounds__(256) void k_fin2(const unsigned* __restrict__ pair, const int* __restrict__ base,
                                              const int* __restrict__ deg, const int* __restrict__ pbase,
                                              int* __restrict__ row_start, int* __restrict__ col) {
    __shared__ unsigned lp[BCAP];
    __shared__ int loc[129];
    __shared__ int cur[128];
    int b = blockIdx.x, t = threadIdx.x;
    int s0 = base[b], n = base[b + 1] - s0;
    int g0 = b * 128;
    if (t == 0) {
        int run = pbase[b];
        for (int i = 0; i < 128; ++i) {
            loc[i] = run;
            int d = (g0 + i < NN) ? deg[g0 + i] : 0;
            run += (d + 15) & ~15;
        }
    }
    __syncthreads();
    if (t < 128 && g0 + t < NN) row_start[g0 + t] = loc[t];
    if (b == NBUCK - 1 && t == 0) row_start[NN] = pbase[NBUCK];
    if (t < 128) cur[t] = loc[t];
    __syncthreads();
    bool lds_ok = (n <= BCAP);
    if (lds_ok) {
        for (int i = t; i < n; i += 256) lp[i] = pair[s0 + i];
        __syncthreads();
        for (int i = t; i < n; i += 256) {
            unsigned v = lp[i];
            int pos = atomicAdd(&cur[v & 127u], 1);
            col[pos] = (int)(v >> 7);
        }
    } else {
        for (int i = t; i < n; i += 256) {
            unsigned v = pair[s0 + i];
            int pos = atomicAdd(&cur[v & 127u], 1);
            col[pos] = (int)(v >> 7);
        }
    }
    __syncthreads();
    if (t < 128 && g0 + t < NN) {
        int d = deg[g0 + t];
        int pd = (d + 15) & ~15;
        int s = loc[t];
        for (int k = d; k < pd; ++k) col[s + k] = NN;   // zero-row pads
    }
}

// ---------------- W prep (all 3 layers): Wt[l][n][k] = bf16(Wl[k][n]) ----------------
__global__ __launch_bounds__(256) void k_wprep3(const float* __restrict__ W1, const float* __restrict__ W2,
                                                const float* __restrict__ W3, unsigned short* __restrict__ Wt) {
    int which = blockIdx.x >> 6;                 // 64 blocks per weight
    const float* W = (which == 0) ? W1 : (which == 1) ? W2 : W3;
    int idx = (blockIdx.x & 63) * 256 + threadIdx.x;   // 16384 per weight
    int k = idx >> 7, n = idx & 127;
    Wt[(size_t)which * F * F + n * F + k] = f2b(W[idx]);
}

// ---------------- MFMA GEMM: C8[r,:] = fp8(dinv[r] * (A[r,:] @ W)), fp32 acc ----------
template <bool FP32IN>
__global__ __launch_bounds__(256) void k_gemm_mfma(const void* __restrict__ Av,
                                                   const unsigned short* __restrict__ Wt,
                                                   const float* __restrict__ dinv,
                                                   unsigned char* __restrict__ C8) {
    __shared__ unsigned short Ws[F * F];  // 32 KB, swizzled: byte ^= (n&7)<<4
    int tid = threadIdx.x;
    int wid = tid >> 6;
    int lane = tid & 63;
    int l15 = lane & 15, l4 = lane >> 4;
    int row0 = blockIdx.x * 128 + wid * 32;

    bf16x8 af[2][4];
#pragma unroll
    for (int mf = 0; mf < 2; ++mf) {
        int r = row0 + mf * 16 + l15;
        if (r > NN - 1) r = NN - 1;
        if (FP32IN) {
            const float* rp = (const float*)Av + (size_t)r * F;
#pragma unroll
            for (int ks = 0; ks < 4; ++ks) {
                float4 v0 = *(const float4*)(rp + ks * 32 + l4 * 8);
                float4 v1 = *(const float4*)(rp + ks * 32 + l4 * 8 + 4);
                bf16x8 a;
                a[0] = (__bf16)v0.x; a[1] = (__bf16)v0.y; a[2] = (__bf16)v0.z; a[3] = (__bf16)v0.w;
                a[4] = (__bf16)v1.x; a[5] = (__bf16)v1.y; a[6] = (__bf16)v1.z; a[7] = (__bf16)v1.w;
                af[mf][ks] = a;
            }
        } else {
            const unsigned short* rp = (const unsigned short*)Av + (size_t)r * F;
#pragma unroll
            for (int ks = 0; ks < 4; ++ks)
                af[mf][ks] = *(const bf16x8*)(rp + ks * 32 + l4 * 8);
        }
    }

#pragma unroll
    for (int p = 0; p < 8; ++p) {
        int idx16 = p * 256 + tid;          // 16-byte unit index, 2048 total
        int n = idx16 >> 4;
        float4 v = *(const float4*)((const char*)Wt + (size_t)idx16 * 16);
        *(float4*)((char*)Ws + (((unsigned)idx16 * 16) ^ (unsigned)((n & 7) << 4))) = v;
    }
    __syncthreads();

    f32x4 acc[2][8];
#pragma unroll
    for (int mf = 0; mf < 2; ++mf)
#pragma unroll
        for (int nf = 0; nf < 8; ++nf) acc[mf][nf] = (f32x4){0.f, 0.f, 0.f, 0.f};

#pragma unroll
    for (int ks = 0; ks < 4; ++ks) {
        bf16x8 bfr[8];
#pragma unroll
        for (int nf = 0; nf < 8; ++nf) {
            int n = nf * 16 + l15;
            unsigned byte = (unsigned)(n * 256 + ks * 64 + l4 * 16) ^ (unsigned)((n & 7) << 4);
            bfr[nf] = *(const bf16x8*)((const char*)Ws + byte);
        }
#pragma unroll
        for (int nf = 0; nf < 8; ++nf) {
            acc[0][nf] = __builtin_amdgcn_mfma_f32_16x16x32_bf16(af[0][ks], bfr[nf], acc[0][nf], 0, 0, 0);
            acc[1][nf] = __builtin_amdgcn_mfma_f32_16x16x32_bf16(af[1][ks], bfr[nf], acc[1][nf], 0, 0, 0);
        }
    }

    // write C as fp8 e4m3 (HW cvt). C/D layout: col = lane&15, row = (lane>>4)*4 + reg
#pragma unroll
    for (int mf = 0; mf < 2; ++mf)
#pragma unroll
        for (int reg = 0; reg < 4; ++reg) {
            int r = row0 + mf * 16 + l4 * 4 + reg;
            if (r < NN) {
                float di = dinv[r];
#pragma unroll
                for (int nf = 0; nf < 8; ++nf) {
                    float v = di * acc[mf][nf][reg];
                    int enc = __builtin_amdgcn_cvt_pk_fp8_f32(v, v, 0, false);
                    C8[(size_t)r * F + nf * 16 + l15] = (unsigned char)(enc & 0xff);
                }
            }
        }
}

// ---------------- SpMM aggregation (fp8 gather, fp32 acc, bf16 out) ----------------
// Padded CSR: every row segment is a multiple of 16 edges, pads -> zero row NN.
// NO masks, NO clamps in the inner loop (r11: mask machinery was ~30% of VALU).
// 64 threads = 2 edge slots x 32 lanes; lane covers 4 cols via one dword (4 fp8).
__global__ __launch_bounds__(64) void k_spmm(const unsigned char* __restrict__ xw8,
                                             const int* __restrict__ row_start,
                                             const int* __restrict__ col,
                                             const float* __restrict__ dinv,
                                             const float* __restrict__ bias,
                                             unsigned short* __restrict__ hout,
                                             int do_elu) {
    int i = blockIdx.x;
    int t = threadIdx.x;
    int lc = t & 31;          // col quad: cols 4*lc .. 4*lc+3
    int slot = t >> 5;        // 0/1: which edge of the pair
    int s = row_start[i], e = row_start[i + 1];
    const unsigned* base = (const unsigned*)xw8;   // row j starts at dword j*32
    float a0 = 0.f, a1 = 0.f, a2 = 0.f, a3 = 0.f;
    for (int p = s; p < e; p += 16) {
        int j[8];
        unsigned u[8];
#pragma unroll
        for (int q = 0; q < 8; ++q) j[q] = col[p + q * 2 + slot];
#pragma unroll
        for (int q = 0; q < 8; ++q) u[q] = base[(unsigned)(j[q] * 32 + lc)];
#pragma unroll
        for (int q = 0; q < 8; ++q) {
            auto lo = __builtin_amdgcn_cvt_pk_f32_fp8(u[q], false);
            auto hi = __builtin_amdgcn_cvt_pk_f32_fp8(u[q], true);
            a0 += lo[0]; a1 += lo[1]; a2 += hi[0]; a3 += hi[1];
        }
    }
    a0 += __shfl_xor(a0, 32);
    a1 += __shfl_xor(a1, 32);
    a2 += __shfl_xor(a2, 32);
    a3 += __shfl_xor(a3, 32);
    float di = dinv[i];
    unsigned us = base[(unsigned)(i * 32 + lc)];
    auto slo = __builtin_amdgcn_cvt_pk_f32_fp8(us, false);
    auto shi = __builtin_amdgcn_cvt_pk_f32_fp8(us, true);
    float4 b4 = *(const float4*)&bias[lc * 4];
    float v0 = di * (a0 + slo[0]) + b4.x;
    float v1 = di * (a1 + slo[1]) + b4.y;
    float v2 = di * (a2 + shi[0]) + b4.z;
    float v3 = di * (a3 + shi[1]) + b4.w;
    if (do_elu) {
        v0 = (v0 > 0.f) ? v0 : (__expf(v0) - 1.f);
        v1 = (v1 > 0.f) ? v1 : (__expf(v1) - 1.f);
        v2 = (v2 > 0.f) ? v2 : (__expf(v2) - 1.f);
        v3 = (v3 > 0.f) ? v3 : (__expf(v3) - 1.f);
    }
    if (slot == 0) {
        ushort4 o;
        o.x = f2b(v0); o.y = f2b(v1); o.z = f2b(v2); o.w = f2b(v3);
        *(ushort4*)&hout[(size_t)i * F + lc * 4] = o;
    }
}

// ---------------- graph boundaries by binary search ----------------
__global__ __launch_bounds__(128) void k_gstart(const int* __restrict__ batch, int* __restrict__ gstart) {
    int g = threadIdx.x;
    if (g > NG) return;
    if (g == NG) { gstart[NG] = NN; return; }
    int lo = 0, hi = NN;
    while (lo < hi) { int mid = (lo + hi) >> 1; if (batch[mid] < g) lo = mid + 1; else hi = mid; }
    gstart[g] = lo;
}

// ---------------- mean pool (partial sums, atomic combine) ----------------
__global__ __launch_bounds__(128) void k_pool(const unsigned short* __restrict__ h,
                                              const int* __restrict__ gstart,
                                              float* __restrict__ poolsum) {
    int g = blockIdx.x >> 4, q = blockIdx.x & 15;
    int c = threadIdx.x;
    int s = gstart[g], e = gstart[g + 1];
    int n = e - s;
    int per = (n + 15) >> 4;
    int ss = s + q * per;
    int ee = min(ss + per, e);
    float acc = 0.f;
    for (int i = ss; i < ee; ++i) acc += b2f(h[(size_t)i * F + c]);
    atomicAdd(&poolsum[g * F + c], acc);
}

// ---------------- final MLP ----------------
__global__ __launch_bounds__(64) void k_mlp(const float* __restrict__ poolsum, const int* __restrict__ gstart,
                                            const float* __restrict__ stats,
                                            const float* __restrict__ fw1, const float* __restrict__ fb1,
                                            const float* __restrict__ fw2, const float* __restrict__ fb2,
                                            const float* __restrict__ fw3, const float* __restrict__ fb3,
                                            float* __restrict__ out) {
    __shared__ float gv[F + 8];
    __shared__ float h1[32];
    __shared__ float h2[16];
    int g = blockIdx.x, t = threadIdx.x;
    float cntf = fmaxf((float)(gstart[g + 1] - gstart[g]), 1.0f);
    for (int c = t; c < F; c += 64) gv[c] = poolsum[g * F + c] / cntf;
    if (t < 8) gv[F + t] = stats[g * 8 + t];
    __syncthreads();
    if (t < 32) {
        float a = fb1[t];
        for (int k = 0; k < F + 8; ++k) a += gv[k] * fw1[k * 32 + t];
        h1[t] = fmaxf(a, 0.f);
    }
    __syncthreads();
    if (t < 16) {
        float a = fb2[t];
        for (int k = 0; k < 32; ++k) a += h1[k] * fw2[k * 16 + t];
        h2[t] = fmaxf(a, 0.f);
    }
    __syncthreads();
    if (t == 0) {
        float a = fb3[0];
        for (int k = 0; k < 16; ++k) a += h2[k] * fw3[k];
        out[g] = a;
    }
}

extern "C" void kernel_launch(void* const* d_in, const int* in_sizes, int n_in,
                              void* d_out, int out_size, void* d_ws, size_t ws_size,
                              hipStream_t stream) {
    const float* x     = (const float*)d_in[0];
    const int*   ei    = (const int*)d_in[1];
    const int*   batch = (const int*)d_in[2];
    const float* stats = (const float*)d_in[3];
    const float* W1 = (const float*)d_in[4];
    const float* b1 = (const float*)d_in[5];
    const float* W2 = (const float*)d_in[6];
    const float* b2 = (const float*)d_in[7];
    const float* W3 = (const float*)d_in[8];
    const float* b3 = (const float*)d_in[9];
    const float* fw1 = (const float*)d_in[10];
    const float* fb1 = (const float*)d_in[11];
    const float* fw2 = (const float*)d_in[12];
    const float* fb2 = (const float*)d_in[13];
    const float* fw3 = (const float*)d_in[14];
    const float* fb3 = (const float*)d_in[15];
    float* out = (float*)d_out;

    const int* srcp = ei;
    const int* dstp = ei + NE;

    char* w = (char*)d_ws;
    size_t off = 0;
    auto take = [&](size_t bytes) -> char* {
        char* p = w + off;
        off += (bytes + 255) & ~size_t(255);
        return p;
    };
    int*   row_start = (int*)take((size_t)(NN + 1) * 4);
    int*   col       = (int*)take((size_t)(NE + 15 * NN + 256) * 4);  // padded CSR
    float* dinv      = (float*)take((size_t)NN * 4);
    int*   deg       = (int*)take((size_t)NN * 4);
    int*   gstart    = (int*)take((size_t)(NG + 1) * 4);
    float* poolsum   = (float*)take((size_t)NG * F * 4);
    int*   histg     = (int*)take((size_t)NBLK * NBUCK * 4);
    int*   offs      = (int*)take((size_t)NBUCK * NBLK * 4);
    int*   tot       = (int*)take((size_t)NBUCK * 4);
    int*   base      = (int*)take((size_t)(NBUCK + 1) * 4);
    int*   ptot      = (int*)take((size_t)NBUCK * 4);
    int*   pbase     = (int*)take((size_t)(NBUCK + 1) * 4);
    unsigned* pair   = (unsigned*)take((size_t)NE * 4);
    unsigned short* Wt   = (unsigned short*)take((size_t)3 * F * F * 2);
    unsigned char*  bufA = (unsigned char*)take((size_t)(NN + 1) * F);   // fp8 xw + zero row
    unsigned short* bufB = (unsigned short*)take((size_t)NN * F * 2);    // bf16 h

    hipMemsetAsync(poolsum, 0, (size_t)NG * F * 4, stream);
    hipMemsetAsync(bufA + (size_t)NN * F, 0, F, stream);   // zero row for pads (fp8 +0)

    // CSR build: two-level counting sort + padded finalize
    k_hist<<<NBLK, 256, 0, stream>>>(dstp, histg);
    k_boff<<<NBUCK, NBLK, 0, stream>>>(histg, offs, tot);
    k_scanb<<<1, 1024, 0, stream>>>(tot, base);
    k_place<<<NBLK, 256, 0, stream>>>(srcp, dstp, offs, base, pair);
    k_cnt<<<NBUCK, 256, 0, stream>>>(pair, base, dinv, deg, ptot);
    k_scanp<<<1, 1024, 0, stream>>>(ptot, pbase);
    k_fin2<<<NBUCK, 256, 0, stream>>>(pair, base, deg, pbase, row_start, col);
    k_gstart<<<1, 128, 0, stream>>>(batch, gstart);
    k_wprep3<<<192, 256, 0, stream>>>(W1, W2, W3, Wt);

    const int gemm_grid = (NN + 127) / 128;

    // layer 1 (fp32 input)
    k_gemm_mfma<true><<<gemm_grid, 256, 0, stream>>>(x, Wt, dinv, bufA);
    k_spmm<<<NN, 64, 0, stream>>>(bufA, row_start, col, dinv, b1, bufB, 1);
    // layer 2
    k_gemm_mfma<false><<<gemm_grid, 256, 0, stream>>>(bufB, Wt + F * F, dinv, bufA);
    k_spmm<<<NN, 64, 0, stream>>>(bufA, row_start, col, dinv, b2, bufB, 1);
    // layer 3
    k_gemm_mfma<false><<<gemm_grid, 256, 0, stream>>>(bufB, Wt + 2 * F * F, dinv, bufA);
    k_spmm<<<NN, 64, 0, stream>>>(bufA, row_start, col, dinv, b3, bufB, 0);

    k_pool<<<NG * 16, F, 0, stream>>>(bufB, gstart, poolsum);
    k_mlp<<<NG, 64, 0, stream>>>(poolsum, gstart, stats, fw1, fb1, fw2, fb2, fw3, fb3, out);
}